// Round 1
// baseline (340.240 us; speedup 1.0000x reference)
//
#include <hip/hip_runtime.h>

#define N_PTS 150000
#define NK 27
#define CIN 128
#define COUT 128

typedef __attribute__((ext_vector_type(8))) short bfrag8;   // 8 bf16 (4 VGPRs)
typedef __attribute__((ext_vector_type(4))) float facc4;    // 4 f32 accum

__device__ inline unsigned short f2bf(float f) {
    unsigned u = __builtin_bit_cast(unsigned, f);
    u += 0x7FFFu + ((u >> 16) & 1u);            // RNE (inputs are finite normals)
    return (unsigned short)(u >> 16);
}
__device__ inline unsigned pack2(float a, float b) {
    return (unsigned)f2bf(a) | ((unsigned)f2bf(b) << 16);
}

// ---- prep: fp32 data -> bf16 ----
__global__ void cast_data_kernel(const float* __restrict__ in,
                                 unsigned short* __restrict__ out, int n8) {
    int i = blockIdx.x * blockDim.x + threadIdx.x;
    int stride = gridDim.x * blockDim.x;
    for (; i < n8; i += stride) {
        const float4* p = (const float4*)(in + (size_t)i * 8);
        float4 x = p[0], y = p[1];
        uint4 v;
        v.x = pack2(x.x, x.y); v.y = pack2(x.z, x.w);
        v.z = pack2(y.x, y.y); v.w = pack2(y.z, y.w);
        *(uint4*)(out + (size_t)i * 8) = v;
    }
}

// ---- prep: W[co][k][ci] fp32 -> wk[k][co][ci] bf16 ----
__global__ void prep_weights_kernel(const float* __restrict__ w,
                                    unsigned short* __restrict__ wk, int total4) {
    int i = blockIdx.x * blockDim.x + threadIdx.x;
    if (i >= total4) return;
    int o = i * 4;
    int ci = o & 127;
    int co = (o >> 7) & 127;
    int k  = o >> 14;
    float4 x = *(const float4*)(w + ((size_t)co * NK + k) * CIN + ci);
    uint2 v;
    v.x = pack2(x.x, x.y); v.y = pack2(x.z, x.w);
    *(uint2*)(wk + o) = v;
}

// ---- main: BM=128 x COUT=128 tile, 4 waves, 16x16x32 bf16 MFMA ----
// LDS rows padded to 136 bf16 (272 B) -> 2-way bank aliasing only (free).
template <bool DATA_BF16>
__global__ __launch_bounds__(256, 2)
void octconv_kernel(const void* __restrict__ data_,
                    const unsigned short* __restrict__ wk,
                    const int* __restrict__ nbr,
                    float* __restrict__ out) {
    __shared__ unsigned short ldsA[128 * 136];
    __shared__ unsigned short ldsB[128 * 136];

    const int t  = threadIdx.x;
    const int m0 = blockIdx.x * 128;
    const int w  = t >> 6;
    const int l  = t & 63;
    const int lr = l & 15;     // row-in-tile (A) / col (B,D)
    const int lk = l >> 4;     // k-chunk

    // staging coords: 2 threads per row, 64 bf16 (=128B) each
    const int ar = t >> 1;
    const int ac = (t & 1) * 64;
    const int m  = m0 + ar;

    facc4 acc0[8], acc1[8];
    const facc4 fz = {0.f, 0.f, 0.f, 0.f};
#pragma unroll
    for (int i = 0; i < 8; ++i) { acc0[i] = fz; acc1[i] = fz; }

    const unsigned short* aP0 = &ldsA[(w * 32 + lr) * 136 + lk * 8];
    const unsigned short* aP1 = aP0 + 16 * 136;

    for (int k = 0; k < NK; ++k) {
        // ---- stage A: gather 128 rows (bf16) into ldsA ----
        int idx = (m < N_PTS) ? nbr[m * NK + k] : -1;
        uint4* dst = (uint4*)&ldsA[ar * 136 + ac];
        if (idx >= 0) {
            if (DATA_BF16) {
                const uint4* src =
                    (const uint4*)((const unsigned short*)data_ + (size_t)idx * CIN + ac);
#pragma unroll
                for (int i = 0; i < 8; ++i) dst[i] = src[i];
            } else {
                const float4* src =
                    (const float4*)((const float*)data_ + (size_t)idx * CIN + ac);
#pragma unroll
                for (int i = 0; i < 8; ++i) {
                    float4 x = src[2 * i], y = src[2 * i + 1];
                    uint4 v;
                    v.x = pack2(x.x, x.y); v.y = pack2(x.z, x.w);
                    v.z = pack2(y.x, y.y); v.w = pack2(y.z, y.w);
                    dst[i] = v;
                }
            }
        } else {
            const uint4 z = {0, 0, 0, 0};
#pragma unroll
            for (int i = 0; i < 8; ++i) dst[i] = z;
        }
        // ---- stage B: wk[k] (32 KB) into ldsB ----
        {
            const uint4* bsrc = (const uint4*)(wk + (size_t)k * (COUT * CIN) + ar * CIN + ac);
            uint4* bdst = (uint4*)&ldsB[ar * 136 + ac];
#pragma unroll
            for (int i = 0; i < 8; ++i) bdst[i] = bsrc[i];
        }
        __syncthreads();
        // ---- MFMA: cin = 4 steps of 32 ----
#pragma unroll
        for (int kk = 0; kk < 4; ++kk) {
            bfrag8 a0 = *(const bfrag8*)(aP0 + kk * 32);
            bfrag8 a1 = *(const bfrag8*)(aP1 + kk * 32);
#pragma unroll
            for (int ct = 0; ct < 8; ++ct) {
                bfrag8 b = *(const bfrag8*)&ldsB[(ct * 16 + lr) * 136 + kk * 32 + lk * 8];
                acc0[ct] = __builtin_amdgcn_mfma_f32_16x16x32_bf16(a0, b, acc0[ct], 0, 0, 0);
                acc1[ct] = __builtin_amdgcn_mfma_f32_16x16x32_bf16(a1, b, acc1[ct], 0, 0, 0);
            }
        }
        __syncthreads();
    }
    // ---- epilogue: C/D layout col=lane&15, row=(lane>>4)*4+reg ----
    const int rbase = m0 + w * 32 + lk * 4;
#pragma unroll
    for (int ct = 0; ct < 8; ++ct) {
#pragma unroll
        for (int r = 0; r < 4; ++r) {
            int row0 = rbase + r;
            if (row0 < N_PTS) out[(size_t)row0 * COUT + ct * 16 + lr] = acc0[ct][r];
            int row1 = row0 + 16;
            if (row1 < N_PTS) out[(size_t)row1 * COUT + ct * 16 + lr] = acc1[ct][r];
        }
    }
}

// ---- emergency fallback (ws too small): plain fp32 ----
__global__ void naive_kernel(const float* __restrict__ data, const float* __restrict__ wgt,
                             const int* __restrict__ nbr, float* __restrict__ out) {
    int mm = blockIdx.x;
    int co = threadIdx.x;
    if (mm >= N_PTS) return;
    float acc = 0.f;
    for (int k = 0; k < NK; ++k) {
        int idx = nbr[mm * NK + k];
        if (idx < 0) continue;
        const float* d  = data + (size_t)idx * CIN;
        const float* wp = wgt + ((size_t)co * NK + k) * CIN;
        for (int ci = 0; ci < CIN; ++ci) acc += d[ci] * wp[ci];
    }
    out[(size_t)mm * COUT + co] = acc;
}

extern "C" void kernel_launch(void* const* d_in, const int* in_sizes, int n_in,
                              void* d_out, int out_size, void* d_ws, size_t ws_size,
                              hipStream_t stream) {
    const float* data = (const float*)d_in[0];
    const float* wgt  = (const float*)d_in[1];
    const int*   nbr  = (const int*)d_in[2];
    float*       out  = (float*)d_out;

    const size_t wk_bytes   = (size_t)NK * COUT * CIN * 2;      // 884,736
    const size_t dbf_bytes  = (size_t)N_PTS * CIN * 2;          // 38,400,000

    if (ws_size < wk_bytes) {
        naive_kernel<<<N_PTS, COUT, 0, stream>>>(data, wgt, nbr, out);
        return;
    }
    unsigned short* wk = (unsigned short*)d_ws;
    prep_weights_kernel<<<(NK * COUT * CIN / 4 + 255) / 256, 256, 0, stream>>>(
        wgt, wk, NK * COUT * CIN / 4);

    const int grid = (N_PTS + 127) / 128;
    if (ws_size >= wk_bytes + dbf_bytes) {
        unsigned short* dbf = (unsigned short*)((char*)d_ws + wk_bytes);  // wk_bytes % 256 == 0
        cast_data_kernel<<<2048, 256, 0, stream>>>(data, dbf, N_PTS * CIN / 8);
        octconv_kernel<true><<<grid, 256, 0, stream>>>(dbf, wk, nbr, out);
    } else {
        octconv_kernel<false><<<grid, 256, 0, stream>>>(data, wk, nbr, out);
    }
}